// Round 2
// baseline (271.940 us; speedup 1.0000x reference)
//
#include <hip/hip_runtime.h>
#include <hip/hip_cooperative_groups.h>

namespace cg = cooperative_groups;

#define N_FEAT 128
#define HID 256
#define OUT_CH 128

#define NB 256        // CSR-build histogram chunks (== grid size of coop kernel)
#define NJ 40         // column blocks: ceil(10000/256)
#define MAXN 10240    // LDS histogram capacity (N=10000)

typedef unsigned short u16;
typedef _Float16 f16x8 __attribute__((ext_vector_type(8)));
typedef float f32x4 __attribute__((ext_vector_type(4)));

// ---------------- f16 pack/unpack helpers ----------------
__device__ __forceinline__ unsigned pack_f16x2(float lo, float hi) {
    union { _Float16 h[2]; unsigned u; } c;
    c.h[0] = (_Float16)lo;
    c.h[1] = (_Float16)hi;
    return c.u;
}
__device__ __forceinline__ float2 unpack_f16x2(unsigned u) {
    union { unsigned u; _Float16 h[2]; } c;
    c.u = u;
    return make_float2((float)c.h[0], (float)c.h[1]);
}
__device__ __forceinline__ u16 f16u(float f) {
    union { _Float16 h; u16 u; } c;
    c.h = (_Float16)f;
    return c.u;
}

// ---------------- Cooperative CSR build + prescale (replaces 5 kernels) ----
// P1: per-block LDS histograms -> bh            [256 blocks]
// P2: column scan + block-local count scan      [blocks 0..39]
//     ∥ W1/W2 -> f16 transposed                 [blocks 40..255]
// P3: segment-base scan -> row_start            [blocks 0..39]
//     ∥ prescale x*dinv -> f16 table            [blocks 40..255]
// P4: scatter via LDS cursors -> csr_src        [256 blocks]
// grid.sync() provides agent-scope release/acquire (cross-XCD L2 safe).
__global__ __launch_bounds__(256)
void csr_coop(const int* __restrict__ dst, const int* __restrict__ src,
              u16* __restrict__ bh, int* __restrict__ csr_src,
              int* __restrict__ row_start, int* __restrict__ segsum,
              float* __restrict__ dinv,
              const float* __restrict__ x, unsigned* __restrict__ xs_b,
              const float* __restrict__ W1, const float* __restrict__ W2,
              u16* __restrict__ W1t, u16* __restrict__ W2t,
              int E, int N, int chunk) {
    cg::grid_group grid = cg::this_grid();
    __shared__ int smem[MAXN];
    const int tid = threadIdx.x;
    const int bid = blockIdx.x;

    // ---- P1: histogram ----
    for (int i = tid; i < N; i += 256) smem[i] = 0;
    __syncthreads();
    {
        int base = bid * chunk;
        int lim = min(chunk, E - base);
        for (int i = tid; i < lim; i += 256) {
            int d = dst[base + i];
            if (d >= 0 && d < N) atomicAdd(&smem[d], 1);
        }
    }
    __syncthreads();
    {
        u16* outp = bh + (size_t)bid * N;
        for (int i = tid; i < N; i += 256) outp[i] = (u16)smem[i];
    }

    grid.sync();

    // ---- P2 ----
    int run = 0, local_excl = 0;   // persist into P3 (same kernel)
    if (bid < NJ) {
        int j = bid * 256 + tid;
        if (j < N) {
            #pragma unroll 8
            for (int b = 0; b < NB; b++) {
                size_t idx = (size_t)b * N + j;
                int t = bh[idx];
                bh[idx] = (u16)run;
                run += t;
            }
            dinv[j] = rsqrtf((float)(run + 1));
        }
        // block-local exclusive scan of per-column counts
        int lane = tid & 63, wv = tid >> 6;
        int incl = run;
        #pragma unroll
        for (int off = 1; off < 64; off <<= 1) {
            int t = __shfl_up(incl, off, 64);
            if (lane >= off) incl += t;
        }
        if (lane == 63) smem[wv] = incl;
        __syncthreads();
        int wbase = 0;
        #pragma unroll
        for (int k = 0; k < 4; k++)
            if (k < wv) wbase += smem[k];
        local_excl = wbase + (incl - run);
        if (tid == 255) segsum[bid] = wbase + incl;   // block total
    } else {
        // weight transpose -> f16 (small; reads L2/L3-cached)
        int t = (bid - NJ) * 256 + tid;
        const int stride = (256 - NJ) * 256;
        const int TOT = N_FEAT * HID + HID * OUT_CH;
        for (; t < TOT; t += stride) {
            if (t < N_FEAT * HID) {            // W1t[n][k] = W1[k][n]
                int n = t >> 7, k = t & 127;
                W1t[t] = f16u(W1[(size_t)k * HID + n]);
            } else {                           // W2t[n][k] = W2[k][n]
                int j2 = t - N_FEAT * HID;
                int n = j2 >> 8, k = j2 & 255;
                W2t[j2] = f16u(W2[(size_t)k * OUT_CH + n]);
            }
        }
    }

    grid.sync();

    // ---- P3 ----
    if (bid < NJ) {
        if (tid < 64) {
            int v = (tid < NJ) ? segsum[tid] : 0;
            int incl = v;
            #pragma unroll
            for (int off = 1; off < 64; off <<= 1) {
                int t = __shfl_up(incl, off, 64);
                if (tid >= off) incl += t;
            }
            int excl = incl - v;
            int base = __shfl(excl, bid, 64);
            int total = __shfl(incl, NJ - 1, 64);
            if (tid == 0) {
                smem[64] = base;
                if (bid == 0) row_start[N] = total;
            }
        }
        __syncthreads();
        int base = smem[64];
        int j = bid * 256 + tid;
        if (j < N) row_start[j] = base + local_excl;
    } else {
        // prescale: xs_b[n] = f16(dinv[n] * x[n,:])
        const int total4 = N * N_FEAT / 4;
        int i = (bid - NJ) * 256 + tid;
        const int stride = (256 - NJ) * 256;
        for (; i < total4; i += stride) {
            int row = i >> 5;                  // 32 float4 per 128-f row
            float d = dinv[row];
            float4 v = ((const float4*)x)[i];
            uint2 p;
            p.x = pack_f16x2(v.x * d, v.y * d);
            p.y = pack_f16x2(v.z * d, v.w * d);
            ((uint2*)xs_b)[i] = p;
        }
    }

    grid.sync();

    // ---- P4: scatter ----
    {
        const u16* basep = bh + (size_t)bid * N;
        for (int i = tid; i < N; i += 256)
            smem[i] = row_start[i] + (int)basep[i];
        __syncthreads();
        int base = bid * chunk;
        int lim = min(chunk, E - base);
        for (int i = tid; i < lim; i += 256) {
            int e = base + i;
            int d = dst[e];
            if (d < 0 || d >= N) continue;
            int pos = atomicAdd(&smem[d], 1);
            if ((unsigned)pos < (unsigned)E) csr_src[pos] = src[e];
        }
    }
}

// ---------------- Aggregation (f16 table, fp32 accumulate) ----------------
// Structure proven over rounds 7-14: 4 waves/block, one node/wave, 64 lanes x
// f16x2, software-pipelined batch-8 edge loop.
template <bool EPILOGUE, bool F16OUT>
__global__ __launch_bounds__(256)
void agg_kernel(const unsigned* __restrict__ featb,
                const float* __restrict__ dinv,
                const int* __restrict__ row_start,
                const int* __restrict__ csr_src,
                const float* __restrict__ bias,
                void* __restrict__ out, int N) {
    int wave = threadIdx.x >> 6;
    int n = blockIdx.x * 4 + wave;
    if (n >= N) return;
    int f = threadIdx.x & 63;
    float dn = dinv[n];
    float2 v = unpack_f16x2(featb[(size_t)n * 64 + f]);
    float accx = v.x;
    float accy = v.y;
    int e0 = row_start[n];
    int e1 = row_start[n + 1];
    int e = e0;
    if (e + 8 <= e1) {
        int s_cur[8];
        #pragma unroll
        for (int j = 0; j < 8; j++) s_cur[j] = csr_src[e + j];
        e += 8;
        for (; e + 8 <= e1; e += 8) {
            unsigned w[8];
            #pragma unroll
            for (int j = 0; j < 8; j++) w[j] = featb[(size_t)s_cur[j] * 64 + f];
            int s_nxt[8];
            #pragma unroll
            for (int j = 0; j < 8; j++) s_nxt[j] = csr_src[e + j];
            #pragma unroll
            for (int j = 0; j < 8; j++) {
                float2 u = unpack_f16x2(w[j]);
                accx += u.x;
                accy += u.y;
            }
            #pragma unroll
            for (int j = 0; j < 8; j++) s_cur[j] = s_nxt[j];
        }
        unsigned w[8];
        #pragma unroll
        for (int j = 0; j < 8; j++) w[j] = featb[(size_t)s_cur[j] * 64 + f];
        #pragma unroll
        for (int j = 0; j < 8; j++) {
            float2 u = unpack_f16x2(w[j]);
            accx += u.x;
            accy += u.y;
        }
    }
    for (; e + 4 <= e1; e += 4) {
        int s0 = csr_src[e], s1 = csr_src[e + 1];
        int s2 = csr_src[e + 2], s3 = csr_src[e + 3];
        unsigned w0 = featb[(size_t)s0 * 64 + f];
        unsigned w1 = featb[(size_t)s1 * 64 + f];
        unsigned w2 = featb[(size_t)s2 * 64 + f];
        unsigned w3 = featb[(size_t)s3 * 64 + f];
        float2 u0 = unpack_f16x2(w0), u1 = unpack_f16x2(w1);
        float2 u2 = unpack_f16x2(w2), u3 = unpack_f16x2(w3);
        accx += u0.x + u1.x + u2.x + u3.x;
        accy += u0.y + u1.y + u2.y + u3.y;
    }
    for (; e < e1; ++e) {
        float2 u = unpack_f16x2(featb[(size_t)csr_src[e] * 64 + f]);
        accx += u.x;
        accy += u.y;
    }
    accx *= dn;
    accy *= dn;
    if (EPILOGUE) {
        float2 b = ((const float2*)bias)[f];
        accx = fmaxf(accx + b.x, 0.0f);
        accy = fmaxf(accy + b.y, 0.0f);
    }
    if (F16OUT) {
        ((unsigned*)out)[(size_t)n * 64 + f] = pack_f16x2(accx, accy);
    } else {
        float2 r;
        r.x = accx;
        r.y = accy;
        ((float2*)out)[(size_t)n * 64 + f] = r;
    }
}

// ---------------- f16 MFMA GEMM: C[M,N] = A[M,K] @ Bt[N,K]^T ----------------
// 64x64 tile, 4 waves; wave w owns rows [w*16,w*16+16) x 64 cols = 4 accum
// frags of mfma_f32_16x16x32_f16 (fp32 accumulate). LDS tiles XOR-swizzled
// (chunk ^ (row&7)) so ds_read_b128 fragment loads are conflict-free (G4/T2).
template <bool BIAS_RELU, bool RSCALE>
__global__ __launch_bounds__(256)
void gemm16_kernel(const u16* __restrict__ A,    // [Mpad][K] f16 row-major
                   const u16* __restrict__ Bt,   // [N][K]   f16 row-major
                   const float* __restrict__ bias,
                   const float* __restrict__ rscale,
                   u16* __restrict__ C,          // [M][N]   f16 row-major
                   int M, int N, int K) {
    __shared__ __align__(16) u16 As[64][64];
    __shared__ __align__(16) u16 Bs[64][64];
    int tid = threadIdx.x;
    int w = tid >> 6;
    int l = tid & 63;
    int m0 = blockIdx.y * 64;
    int n0 = blockIdx.x * 64;

    f32x4 acc[4];
    const f32x4 zero = {0.f, 0.f, 0.f, 0.f};
    #pragma unroll
    for (int n = 0; n < 4; n++) acc[n] = zero;

    int rowA = w * 16 + (l & 15);   // A-frag row (M dim)
    int cbase = l >> 4;             // k-chunk sub-index 0..3

    for (int k0 = 0; k0 < K; k0 += 64) {
        #pragma unroll
        for (int t = 0; t < 2; t++) {
            int q = tid + t * 256;        // 512 16B-chunks per 64x64 f16 tile
            int r = q >> 3;
            int c = q & 7;
            f16x8 av = *(const f16x8*)(A + (size_t)(m0 + r) * K + k0 + c * 8);
            *(f16x8*)&As[r][(c ^ (r & 7)) * 8] = av;
            f16x8 bv = *(const f16x8*)(Bt + (size_t)(n0 + r) * K + k0 + c * 8);
            *(f16x8*)&Bs[r][(c ^ (r & 7)) * 8] = bv;
        }
        __syncthreads();
        #pragma unroll
        for (int kc = 0; kc < 2; kc++) {
            int ch = kc * 4 + cbase;      // lane's 8-elem k-chunk within 64
            f16x8 af = *(const f16x8*)&As[rowA][(ch ^ (rowA & 7)) * 8];
            #pragma unroll
            for (int n = 0; n < 4; n++) {
                int rb = n * 16 + (l & 15);
                f16x8 bf = *(const f16x8*)&Bs[rb][(ch ^ (rb & 7)) * 8];
                acc[n] = __builtin_amdgcn_mfma_f32_16x16x32_f16(af, bf, acc[n], 0, 0, 0);
            }
        }
        __syncthreads();
    }
    // epilogue: D lane mapping col = lane&15, row = (lane>>4)*4 + reg (m89)
    int r0 = (l >> 4) * 4;
    int col_l = l & 15;
    #pragma unroll
    for (int r = 0; r < 4; r++) {
        int m = m0 + w * 16 + r0 + r;
        if (m >= M) continue;
        float rs = RSCALE ? rscale[m] : 1.0f;
        #pragma unroll
        for (int n = 0; n < 4; n++) {
            int col = n0 + n * 16 + col_l;
            float v = acc[n][r];
            if (RSCALE) v *= rs;
            if (BIAS_RELU) v = fmaxf(v + bias[col], 0.0f);
            C[(size_t)m * N + col] = f16u(v);
        }
    }
}

// ---------------- launch ----------------

static inline size_t align512(size_t x) { return (x + 511) & ~(size_t)511; }

extern "C" void kernel_launch(void* const* d_in, const int* in_sizes, int n_in,
                              void* d_out, int out_size, void* d_ws, size_t ws_size,
                              hipStream_t stream) {
    const float* x = (const float*)d_in[0];
    const int* ei = (const int*)d_in[1];
    const float* W1 = (const float*)d_in[2];
    const float* b1 = (const float*)d_in[3];
    const float* W2 = (const float*)d_in[4];
    const float* b2 = (const float*)d_in[5];
    float* out = (float*)d_out;

    const int N = in_sizes[0] / N_FEAT;      // 10000
    const int E = in_sizes[1] / 2;           // 640000
    const int* src = ei;
    const int* dst = ei + E;

    const int Mpad = ((N + 63) / 64) * 64;   // 10048 (MFMA staging pad)

    // workspace carve-up (~21 MB)
    char* ws = (char*)d_ws;
    size_t off = 0;
    float* dinv = (float*)(ws + off);    off += align512((size_t)N * 4);
    int* segsum = (int*)(ws + off);      off += align512((size_t)64 * 4);
    int* row_start = (int*)(ws + off);   off += align512((size_t)(N + 1) * 4);
    int* csr_src = (int*)(ws + off);     off += align512((size_t)E * 4);
    unsigned* xs_b = (unsigned*)(ws + off);  off += align512((size_t)N * 64 * 4);
    u16* agg1h = (u16*)(ws + off);       off += align512((size_t)Mpad * N_FEAT * 2);
    u16* h16 = (u16*)(ws + off);         off += align512((size_t)Mpad * HID * 2);
    u16* t16 = (u16*)(ws + off);         off += align512((size_t)N * OUT_CH * 2);
    u16* W1t = (u16*)(ws + off);         off += align512((size_t)HID * N_FEAT * 2);
    u16* W2t = (u16*)(ws + off);         off += align512((size_t)OUT_CH * HID * 2);
    u16* bh = (u16*)(ws + off);          off += align512((size_t)NB * N * 2);
    (void)ws_size;
    int chunk = (E + NB - 1) / NB;
    int Ev = E, Nv = N;

    // 1. CSR build + prescale + weight convert: ONE cooperative kernel
    {
        const int* dstp = dst;
        const int* srcp = src;
        void* kargs[] = {
            (void*)&dstp, (void*)&srcp, (void*)&bh, (void*)&csr_src,
            (void*)&row_start, (void*)&segsum, (void*)&dinv,
            (void*)&x, (void*)&xs_b, (void*)&W1, (void*)&W2,
            (void*)&W1t, (void*)&W2t, (void*)&Ev, (void*)&Nv, (void*)&chunk
        };
        hipLaunchCooperativeKernel(reinterpret_cast<void*>(csr_coop),
                                   dim3(NB), dim3(256), kargs, 0, stream);
    }

    // 2. agg1h = f16(A_norm @ x)
    agg_kernel<false, true><<<(N + 3) / 4, 256, 0, stream>>>(
        xs_b, dinv, row_start, csr_src, nullptr, agg1h, N);

    // 3. h16 = f16(relu(agg1h @ W1 + b1))   [MFMA]
    {
        dim3 grid(HID / 64, Mpad / 64);
        gemm16_kernel<true, false><<<grid, 256, 0, stream>>>(
            agg1h, W1t, b1, nullptr, h16, N, HID, N_FEAT);
    }

    // 4. t16 = f16(dinv[m] * (h16 @ W2))    [MFMA]
    {
        dim3 grid(OUT_CH / 64, Mpad / 64);
        gemm16_kernel<false, true><<<grid, 256, 0, stream>>>(
            h16, W2t, nullptr, dinv, t16, N, OUT_CH, HID);
    }

    // 5. out = relu(A_norm-aggregate of t16 + b2)
    agg_kernel<true, false><<<(N + 3) / 4, 256, 0, stream>>>(
        (const unsigned*)t16, dinv, row_start, csr_src, b2, out, N);
}

// Round 3
// 179.111 us; speedup vs baseline: 1.5183x; 1.5183x over previous
//
#include <hip/hip_runtime.h>

#define N_FEAT 128
#define HID 256
#define OUT_CH 128

#define NB 256        // CSR-build blocks (per-block histograms)
#define MAXN 10240    // LDS histogram capacity (N=10000)

typedef unsigned short u16;
typedef _Float16 f16x8 __attribute__((ext_vector_type(8)));
typedef float f32x4 __attribute__((ext_vector_type(4)));

// ---------------- f16 pack/unpack helpers ----------------
__device__ __forceinline__ unsigned pack_f16x2(float lo, float hi) {
    union { _Float16 h[2]; unsigned u; } c;
    c.h[0] = (_Float16)lo;
    c.h[1] = (_Float16)hi;
    return c.u;
}
__device__ __forceinline__ float2 unpack_f16x2(unsigned u) {
    union { unsigned u; _Float16 h[2]; } c;
    c.u = u;
    return make_float2((float)c.h[0], (float)c.h[1]);
}
__device__ __forceinline__ u16 f16u(float f) {
    union { _Float16 h; u16 u; } c;
    c.h = (_Float16)f;
    return c.u;
}

// ---------------- CSR build: LDS-histogram counting sort ----------------

__global__ __launch_bounds__(256)
void hist_kernel(const int* __restrict__ dst, u16* __restrict__ bh,
                 int E, int N, int chunk) {
    __shared__ int hist[MAXN];
    for (int i = threadIdx.x; i < N; i += 256) hist[i] = 0;
    __syncthreads();
    int base = blockIdx.x * chunk;
    int lim = min(chunk, E - base);
    for (int i = threadIdx.x; i < lim; i += 256) {
        int d = dst[base + i];
        if (d >= 0 && d < N) atomicAdd(&hist[d], 1);
    }
    __syncthreads();
    u16* out = bh + (size_t)blockIdx.x * N;
    for (int i = threadIdx.x; i < N; i += 256) out[i] = (u16)hist[i];
}

// Fused column scan: bh[b][j] <- per-column exclusive block prefix; also
// emits counts + dinv. (Coop-kernel fusion of the whole CSR chain measured
// 141us vs ~50us for this separate-kernel chain -- grid.sync too costly.)
__global__ __launch_bounds__(256)
void colscan_kernel(u16* __restrict__ bh,
                    int* __restrict__ counts, float* __restrict__ dinv, int N) {
    int j = blockIdx.x * 256 + threadIdx.x;
    if (j >= N) return;
    int run = 0;
    #pragma unroll 8
    for (int b = 0; b < NB; b++) {
        size_t idx = (size_t)b * N + j;
        int t = bh[idx];
        bh[idx] = (u16)run;
        run += t;
    }
    counts[j] = run;
    dinv[j] = rsqrtf((float)(run + 1));
}

// Single-block hybrid scan: row_start = exclusive-scan(counts).
#define SCAN_T 1024
#define SCAN_MAX_PER 16
__global__ __launch_bounds__(SCAN_T)
void scan_kernel(const int* __restrict__ counts,
                 int* __restrict__ row_start, int n) {
    int tid = threadIdx.x;
    int per = (n + SCAN_T - 1) / SCAN_T;
    int base = tid * per;
    int local[SCAN_MAX_PER];
    int sum = 0;
    for (int j = 0; j < per; j++) {
        int i = base + j;
        int c = (i < n) ? counts[i] : 0;
        local[j] = sum;
        sum += c;
    }
    int lane = tid & 63;
    int wave = tid >> 6;
    int incl = sum;
    #pragma unroll
    for (int off = 1; off < 64; off <<= 1) {
        int t = __shfl_up(incl, off, 64);
        if (lane >= off) incl += t;
    }
    __shared__ int wsum[16];
    __shared__ int woff[16];
    if (lane == 63) wsum[wave] = incl;
    __syncthreads();
    if (wave == 0) {
        int w = (lane < 16) ? wsum[lane] : 0;
        int v = w;
        #pragma unroll
        for (int off = 1; off < 16; off <<= 1) {
            int t = __shfl_up(v, off, 64);
            if (lane >= off) v += t;
        }
        if (lane < 16) woff[lane] = v - w;
    }
    __syncthreads();
    int thread_excl = woff[wave] + (incl - sum);
    for (int j = 0; j < per; j++) {
        int i = base + j;
        if (i < n) row_start[i] = thread_excl + local[j];
    }
    if (tid == SCAN_T - 1) row_start[n] = thread_excl + sum;
}

// Scatter via LDS cursors (no global atomics).
__global__ __launch_bounds__(256)
void scat_kernel(const int* __restrict__ src, const int* __restrict__ dst,
                 const u16* __restrict__ bh,
                 const int* __restrict__ row_start,
                 int* __restrict__ csr_src, int E, int N, int chunk) {
    __shared__ int cur[MAXN];
    const u16* basep = bh + (size_t)blockIdx.x * N;
    for (int i = threadIdx.x; i < N; i += 256)
        cur[i] = row_start[i] + (int)basep[i];
    __syncthreads();
    int base = blockIdx.x * chunk;
    int lim = min(chunk, E - base);
    for (int i = threadIdx.x; i < lim; i += 256) {
        int e = base + i;
        int d = dst[e];
        if (d < 0 || d >= N) continue;
        int pos = atomicAdd(&cur[d], 1);
        if ((unsigned)pos < (unsigned)E) csr_src[pos] = src[e];
    }
}

// ---------------- prescale (f16 table) + W1/W2 -> f16 transposed ----------------
__global__ void prescale_kernel(const float* __restrict__ x,
                                const float* __restrict__ dinv,
                                unsigned* __restrict__ xs_b,
                                const float* __restrict__ W1,
                                const float* __restrict__ W2,
                                u16* __restrict__ W1t, u16* __restrict__ W2t,
                                int total4) {
    int i = blockIdx.x * blockDim.x + threadIdx.x;
    if (i < total4) {
        int row = i >> 5;                // 32 float4 per 128-f row
        float d = dinv[row];
        float4 v = ((const float4*)x)[i];
        uint2 p;
        p.x = pack_f16x2(v.x * d, v.y * d);
        p.y = pack_f16x2(v.z * d, v.w * d);
        ((uint2*)xs_b)[i] = p;
    } else {
        int j = i - total4;
        if (j < N_FEAT * HID) {          // W1t[n][k] = W1[k][n], f16 [256][128]
            int n = j >> 7, k = j & 127;
            W1t[j] = f16u(W1[(size_t)k * HID + n]);
        } else {
            j -= N_FEAT * HID;           // W2t[n][k] = W2[k][n], f16 [128][256]
            if (j < HID * OUT_CH) {
                int n = j >> 8, k = j & 255;
                W2t[j] = f16u(W2[(size_t)k * OUT_CH + n]);
            }
        }
    }
}

// ---------------- Aggregation: 2 nodes per wave, dual batch-8 pipelines ----
// agg is latency-bound (L2 traffic alone would be ~5us; measured ~50us).
// Single stream = 8 outstanding 256B gathers/wave. Two independent edge
// streams per wave -> 16 outstanding, ~2x memory-level parallelism, ~75 VGPR
// (no spill, unlike the rejected batch-32).
__device__ __forceinline__ void agg_tail(const unsigned* __restrict__ featb,
                                         const int* __restrict__ csr_src,
                                         int e, int e1, int f,
                                         float& accx, float& accy) {
    for (; e + 4 <= e1; e += 4) {
        int s0 = csr_src[e], s1 = csr_src[e + 1];
        int s2 = csr_src[e + 2], s3 = csr_src[e + 3];
        unsigned w0 = featb[(size_t)s0 * 64 + f];
        unsigned w1 = featb[(size_t)s1 * 64 + f];
        unsigned w2 = featb[(size_t)s2 * 64 + f];
        unsigned w3 = featb[(size_t)s3 * 64 + f];
        float2 u0 = unpack_f16x2(w0), u1 = unpack_f16x2(w1);
        float2 u2 = unpack_f16x2(w2), u3 = unpack_f16x2(w3);
        accx += u0.x + u1.x + u2.x + u3.x;
        accy += u0.y + u1.y + u2.y + u3.y;
    }
    for (; e < e1; ++e) {
        float2 u = unpack_f16x2(featb[(size_t)csr_src[e] * 64 + f]);
        accx += u.x;
        accy += u.y;
    }
}

// Full single-stream path (batch-8 pipelined + tail) for odd cases.
__device__ __forceinline__ void agg_full(const unsigned* __restrict__ featb,
                                         const int* __restrict__ csr_src,
                                         int e, int e1, int f,
                                         float& accx, float& accy) {
    if (e + 8 <= e1) {
        int s_cur[8];
        #pragma unroll
        for (int j = 0; j < 8; j++) s_cur[j] = csr_src[e + j];
        e += 8;
        for (; e + 8 <= e1; e += 8) {
            unsigned w[8];
            #pragma unroll
            for (int j = 0; j < 8; j++) w[j] = featb[(size_t)s_cur[j] * 64 + f];
            int s_nxt[8];
            #pragma unroll
            for (int j = 0; j < 8; j++) s_nxt[j] = csr_src[e + j];
            #pragma unroll
            for (int j = 0; j < 8; j++) {
                float2 u = unpack_f16x2(w[j]);
                accx += u.x;
                accy += u.y;
            }
            #pragma unroll
            for (int j = 0; j < 8; j++) s_cur[j] = s_nxt[j];
        }
        unsigned w[8];
        #pragma unroll
        for (int j = 0; j < 8; j++) w[j] = featb[(size_t)s_cur[j] * 64 + f];
        #pragma unroll
        for (int j = 0; j < 8; j++) {
            float2 u = unpack_f16x2(w[j]);
            accx += u.x;
            accy += u.y;
        }
    }
    agg_tail(featb, csr_src, e, e1, f, accx, accy);
}

template <bool EPILOGUE, bool F16OUT>
__global__ __launch_bounds__(256)
void agg_kernel(const unsigned* __restrict__ featb,
                const float* __restrict__ dinv,
                const int* __restrict__ row_start,
                const int* __restrict__ csr_src,
                const float* __restrict__ bias,
                void* __restrict__ out, int N) {
    int wave = threadIdx.x >> 6;
    int f = threadIdx.x & 63;
    int na = blockIdx.x * 8 + wave * 2;
    if (na >= N) return;
    int nb = na + 1;
    bool hasB = (nb < N);

    float2 va = unpack_f16x2(featb[(size_t)na * 64 + f]);
    float ax = va.x, ay = va.y;
    float bx = 0.f, by = 0.f;
    if (hasB) {
        float2 vb = unpack_f16x2(featb[(size_t)nb * 64 + f]);
        bx = vb.x;
        by = vb.y;
    }
    int ea = row_start[na], ea1 = row_start[na + 1];
    int eb = 0, eb1 = 0;
    if (hasB) { eb = ea1; eb1 = row_start[nb + 1]; }

    if (hasB && ea + 8 <= ea1 && eb + 8 <= eb1) {
        // dual software-pipelined batch-8 loop: 16 outstanding gathers
        int sa[8], sb[8];
        #pragma unroll
        for (int j = 0; j < 8; j++) sa[j] = csr_src[ea + j];
        #pragma unroll
        for (int j = 0; j < 8; j++) sb[j] = csr_src[eb + j];
        ea += 8;
        eb += 8;
        while (ea + 8 <= ea1 && eb + 8 <= eb1) {
            unsigned wa[8], wb[8];
            #pragma unroll
            for (int j = 0; j < 8; j++) wa[j] = featb[(size_t)sa[j] * 64 + f];
            #pragma unroll
            for (int j = 0; j < 8; j++) wb[j] = featb[(size_t)sb[j] * 64 + f];
            int sna[8], snb[8];
            #pragma unroll
            for (int j = 0; j < 8; j++) sna[j] = csr_src[ea + j];
            #pragma unroll
            for (int j = 0; j < 8; j++) snb[j] = csr_src[eb + j];
            #pragma unroll
            for (int j = 0; j < 8; j++) {
                float2 u = unpack_f16x2(wa[j]);
                ax += u.x;
                ay += u.y;
            }
            #pragma unroll
            for (int j = 0; j < 8; j++) {
                float2 u = unpack_f16x2(wb[j]);
                bx += u.x;
                by += u.y;
            }
            #pragma unroll
            for (int j = 0; j < 8; j++) {
                sa[j] = sna[j];
                sb[j] = snb[j];
            }
            ea += 8;
            eb += 8;
        }
        // drain prefetched batches
        unsigned wa[8], wb[8];
        #pragma unroll
        for (int j = 0; j < 8; j++) wa[j] = featb[(size_t)sa[j] * 64 + f];
        #pragma unroll
        for (int j = 0; j < 8; j++) wb[j] = featb[(size_t)sb[j] * 64 + f];
        #pragma unroll
        for (int j = 0; j < 8; j++) {
            float2 u = unpack_f16x2(wa[j]);
            ax += u.x;
            ay += u.y;
        }
        #pragma unroll
        for (int j = 0; j < 8; j++) {
            float2 u = unpack_f16x2(wb[j]);
            bx += u.x;
            by += u.y;
        }
        // unbalanced remainders (Poisson(64): short)
        agg_full(featb, csr_src, ea, ea1, f, ax, ay);
        agg_full(featb, csr_src, eb, eb1, f, bx, by);
    } else {
        agg_full(featb, csr_src, ea, ea1, f, ax, ay);
        if (hasB) agg_full(featb, csr_src, eb, eb1, f, bx, by);
    }

    float dna = dinv[na];
    ax *= dna;
    ay *= dna;
    float2 bias2 = make_float2(0.f, 0.f);
    if (EPILOGUE) {
        bias2 = ((const float2*)bias)[f];
        ax = fmaxf(ax + bias2.x, 0.0f);
        ay = fmaxf(ay + bias2.y, 0.0f);
    }
    if (F16OUT) {
        ((unsigned*)out)[(size_t)na * 64 + f] = pack_f16x2(ax, ay);
    } else {
        float2 r;
        r.x = ax;
        r.y = ay;
        ((float2*)out)[(size_t)na * 64 + f] = r;
    }
    if (hasB) {
        float dnb = dinv[nb];
        bx *= dnb;
        by *= dnb;
        if (EPILOGUE) {
            bx = fmaxf(bx + bias2.x, 0.0f);
            by = fmaxf(by + bias2.y, 0.0f);
        }
        if (F16OUT) {
            ((unsigned*)out)[(size_t)nb * 64 + f] = pack_f16x2(bx, by);
        } else {
            float2 r;
            r.x = bx;
            r.y = by;
            ((float2*)out)[(size_t)nb * 64 + f] = r;
        }
    }
}

// ---------------- f16 MFMA GEMM: C[M,N] = A[M,K] @ Bt[N,K]^T ----------------
// 64x64 tile, 4 waves; wave w owns rows [w*16,w*16+16) x 64 cols = 4 accum
// frags of mfma_f32_16x16x32_f16 (fp32 accumulate). LDS tiles XOR-swizzled
// (chunk ^ (row&7)) so ds_read_b128 fragment loads are conflict-free (G4/T2).
template <bool BIAS_RELU, bool RSCALE>
__global__ __launch_bounds__(256)
void gemm16_kernel(const u16* __restrict__ A,    // [Mpad][K] f16 row-major
                   const u16* __restrict__ Bt,   // [N][K]   f16 row-major
                   const float* __restrict__ bias,
                   const float* __restrict__ rscale,
                   u16* __restrict__ C,          // [M][N]   f16 row-major
                   int M, int N, int K) {
    __shared__ __align__(16) u16 As[64][64];
    __shared__ __align__(16) u16 Bs[64][64];
    int tid = threadIdx.x;
    int w = tid >> 6;
    int l = tid & 63;
    int m0 = blockIdx.y * 64;
    int n0 = blockIdx.x * 64;

    f32x4 acc[4];
    const f32x4 zero = {0.f, 0.f, 0.f, 0.f};
    #pragma unroll
    for (int n = 0; n < 4; n++) acc[n] = zero;

    int rowA = w * 16 + (l & 15);   // A-frag row (M dim)
    int cbase = l >> 4;             // k-chunk sub-index 0..3

    for (int k0 = 0; k0 < K; k0 += 64) {
        #pragma unroll
        for (int t = 0; t < 2; t++) {
            int q = tid + t * 256;        // 512 16B-chunks per 64x64 f16 tile
            int r = q >> 3;
            int c = q & 7;
            f16x8 av = *(const f16x8*)(A + (size_t)(m0 + r) * K + k0 + c * 8);
            *(f16x8*)&As[r][(c ^ (r & 7)) * 8] = av;
            f16x8 bv = *(const f16x8*)(Bt + (size_t)(n0 + r) * K + k0 + c * 8);
            *(f16x8*)&Bs[r][(c ^ (r & 7)) * 8] = bv;
        }
        __syncthreads();
        #pragma unroll
        for (int kc = 0; kc < 2; kc++) {
            int ch = kc * 4 + cbase;      // lane's 8-elem k-chunk within 64
            f16x8 af = *(const f16x8*)&As[rowA][(ch ^ (rowA & 7)) * 8];
            #pragma unroll
            for (int n = 0; n < 4; n++) {
                int rb = n * 16 + (l & 15);
                f16x8 bf = *(const f16x8*)&Bs[rb][(ch ^ (rb & 7)) * 8];
                acc[n] = __builtin_amdgcn_mfma_f32_16x16x32_f16(af, bf, acc[n], 0, 0, 0);
            }
        }
        __syncthreads();
    }
    // epilogue: D lane mapping col = lane&15, row = (lane>>4)*4 + reg (m89)
    int r0 = (l >> 4) * 4;
    int col_l = l & 15;
    #pragma unroll
    for (int r = 0; r < 4; r++) {
        int m = m0 + w * 16 + r0 + r;
        if (m >= M) continue;
        float rs = RSCALE ? rscale[m] : 1.0f;
        #pragma unroll
        for (int n = 0; n < 4; n++) {
            int col = n0 + n * 16 + col_l;
            float v = acc[n][r];
            if (RSCALE) v *= rs;
            if (BIAS_RELU) v = fmaxf(v + bias[col], 0.0f);
            C[(size_t)m * N + col] = f16u(v);
        }
    }
}

// ---------------- launch ----------------

static inline size_t align512(size_t x) { return (x + 511) & ~(size_t)511; }

extern "C" void kernel_launch(void* const* d_in, const int* in_sizes, int n_in,
                              void* d_out, int out_size, void* d_ws, size_t ws_size,
                              hipStream_t stream) {
    const float* x = (const float*)d_in[0];
    const int* ei = (const int*)d_in[1];
    const float* W1 = (const float*)d_in[2];
    const float* b1 = (const float*)d_in[3];
    const float* W2 = (const float*)d_in[4];
    const float* b2 = (const float*)d_in[5];
    float* out = (float*)d_out;

    const int N = in_sizes[0] / N_FEAT;      // 10000
    const int E = in_sizes[1] / 2;           // 640000
    const int* src = ei;
    const int* dst = ei + E;

    const int Mpad = ((N + 63) / 64) * 64;   // 10048 (MFMA staging pad)

    // workspace carve-up (~21 MB)
    char* ws = (char*)d_ws;
    size_t off = 0;
    float* dinv = (float*)(ws + off);    off += align512((size_t)N * 4);
    int* counts = (int*)(ws + off);      off += align512((size_t)N * 4);
    int* row_start = (int*)(ws + off);   off += align512((size_t)(N + 1) * 4);
    int* csr_src = (int*)(ws + off);     off += align512((size_t)E * 4);
    unsigned* xs_b = (unsigned*)(ws + off);  off += align512((size_t)N * 64 * 4);
    u16* agg1h = (u16*)(ws + off);       off += align512((size_t)Mpad * N_FEAT * 2);
    u16* h16 = (u16*)(ws + off);         off += align512((size_t)Mpad * HID * 2);
    u16* t16 = (u16*)(ws + off);         off += align512((size_t)N * OUT_CH * 2);
    u16* W1t = (u16*)(ws + off);         off += align512((size_t)HID * N_FEAT * 2);
    u16* W2t = (u16*)(ws + off);         off += align512((size_t)OUT_CH * HID * 2);
    u16* bh = (u16*)(ws + off);          off += align512((size_t)NB * N * 2);
    (void)ws_size;
    const int chunk = (E + NB - 1) / NB;
    const int NJ = (N + 255) / 256;

    // 1. CSR build (separate kernels -- coop fusion measured 3x slower)
    hist_kernel<<<NB, 256, 0, stream>>>(dst, bh, E, N, chunk);
    colscan_kernel<<<NJ, 256, 0, stream>>>(bh, counts, dinv, N);
    scan_kernel<<<1, SCAN_T, 0, stream>>>(counts, row_start, N);
    scat_kernel<<<NB, 256, 0, stream>>>(src, dst, bh, row_start, csr_src, E, N, chunk);

    // 2. xs_b = f16(dinv[row] * x); tail converts W1/W2 -> f16 transposed
    {
        int total4 = N * N_FEAT / 4;
        int total = total4 + N_FEAT * HID + HID * OUT_CH;
        prescale_kernel<<<(total + 255) / 256, 256, 0, stream>>>(
            x, dinv, xs_b, W1, W2, W1t, W2t, total4);
    }

    // 3. agg1h = f16(A_norm @ x)   [2 nodes/wave dual-pipeline]
    agg_kernel<false, true><<<(N + 7) / 8, 256, 0, stream>>>(
        xs_b, dinv, row_start, csr_src, nullptr, agg1h, N);

    // 4. h16 = f16(relu(agg1h @ W1 + b1))   [MFMA]
    {
        dim3 grid(HID / 64, Mpad / 64);
        gemm16_kernel<true, false><<<grid, 256, 0, stream>>>(
            agg1h, W1t, b1, nullptr, h16, N, HID, N_FEAT);
    }

    // 5. t16 = f16(dinv[m] * (h16 @ W2))    [MFMA]
    {
        dim3 grid(OUT_CH / 64, Mpad / 64);
        gemm16_kernel<false, true><<<grid, 256, 0, stream>>>(
            h16, W2t, nullptr, dinv, t16, N, OUT_CH, HID);
    }

    // 6. out = relu(A_norm-aggregate of t16 + b2)
    agg_kernel<true, false><<<(N + 7) / 8, 256, 0, stream>>>(
        (const unsigned*)t16, dinv, row_start, csr_src, b2, out, N);
}

// Round 4
// 174.566 us; speedup vs baseline: 1.5578x; 1.0260x over previous
//
#include <hip/hip_runtime.h>

#define N_FEAT 128
#define HID 256
#define OUT_CH 128

#define NB 256        // CSR-build blocks (per-block histograms)
#define NJ 40         // column-scan blocks (all co-resident: spin-safe)
#define MAXN 10240    // LDS histogram capacity (N=10000)

typedef unsigned short u16;
typedef _Float16 f16x8 __attribute__((ext_vector_type(8)));
typedef float f32x4 __attribute__((ext_vector_type(4)));

// ---------------- f16 pack/unpack helpers ----------------
__device__ __forceinline__ unsigned pack_f16x2(float lo, float hi) {
    union { _Float16 h[2]; unsigned u; } c;
    c.h[0] = (_Float16)lo;
    c.h[1] = (_Float16)hi;
    return c.u;
}
__device__ __forceinline__ float2 unpack_f16x2(unsigned u) {
    union { unsigned u; _Float16 h[2]; } c;
    c.u = u;
    return make_float2((float)c.h[0], (float)c.h[1]);
}
__device__ __forceinline__ u16 f16u(float f) {
    union { _Float16 h; u16 u; } c;
    c.h = (_Float16)f;
    return c.u;
}

// ---------------- CSR build: LDS-histogram counting sort ----------------

__global__ __launch_bounds__(256)
void hist_kernel(const int* __restrict__ dst, u16* __restrict__ bh,
                 int* __restrict__ flag, int E, int N, int chunk) {
    __shared__ int hist[MAXN];
    if (blockIdx.x == 0 && threadIdx.x < 64) flag[threadIdx.x] = 0;  // scan flags
    for (int i = threadIdx.x; i < N; i += 256) hist[i] = 0;
    __syncthreads();
    int base = blockIdx.x * chunk;
    int lim = min(chunk, E - base);
    for (int i = threadIdx.x; i < lim; i += 256) {
        int d = dst[base + i];
        if (d >= 0 && d < N) atomicAdd(&hist[d], 1);
    }
    __syncthreads();
    u16* out = bh + (size_t)blockIdx.x * N;
    for (int i = threadIdx.x; i < N; i += 256) out[i] = (u16)hist[i];
}

// Fused column scan + global exclusive scan (replaces colscan + scan_kernel).
// 40 blocks, all co-resident (grid << 256 CUs) -> cross-block prefix via
// device-scope atomic flags (value = total+1, 0 = unset); each block's lanes
// poll predecessors in parallel (no serial chain, no grid.sync).
__global__ __launch_bounds__(256)
void colscan_scan_kernel(u16* __restrict__ bh, int* __restrict__ row_start,
                         float* __restrict__ dinv, int* __restrict__ flag,
                         int N) {
    int tid = threadIdx.x;
    int b = blockIdx.x;
    int j = b * 256 + tid;
    int run = 0;
    if (j < N) {
        #pragma unroll 8
        for (int bb = 0; bb < NB; bb++) {
            size_t idx = (size_t)bb * N + j;
            int t = bh[idx];
            bh[idx] = (u16)run;
            run += t;
        }
        dinv[j] = rsqrtf((float)(run + 1));
    }
    // block-local exclusive scan of 256 counts
    __shared__ int wsum[4];
    __shared__ int sbase;
    int lane = tid & 63, wv = tid >> 6;
    int incl = run;
    #pragma unroll
    for (int off = 1; off < 64; off <<= 1) {
        int t = __shfl_up(incl, off, 64);
        if (lane >= off) incl += t;
    }
    if (lane == 63) wsum[wv] = incl;
    __syncthreads();
    int wbase = 0;
    #pragma unroll
    for (int k = 0; k < 4; k++)
        if (k < wv) wbase += wsum[k];
    int local_excl = wbase + (incl - run);
    int T_b = wsum[0] + wsum[1] + wsum[2] + wsum[3];
    // publish own total (value+1; relaxed atomic is self-contained)
    if (tid == 0)
        __hip_atomic_store(&flag[b], T_b + 1, __ATOMIC_RELAXED,
                           __HIP_MEMORY_SCOPE_AGENT);
    // sum predecessors' totals (lanes poll in parallel)
    if (tid < 64) {
        int v = 0;
        if (tid < b) {
            int f;
            do {
                f = __hip_atomic_load(&flag[tid], __ATOMIC_RELAXED,
                                      __HIP_MEMORY_SCOPE_AGENT);
            } while (f == 0);
            v = f - 1;
        }
        #pragma unroll
        for (int off = 1; off < 64; off <<= 1) v += __shfl_xor(v, off, 64);
        if (tid == 0) sbase = v;
    }
    __syncthreads();
    int base = sbase;
    if (j < N) row_start[j] = base + local_excl;
    if (b == NJ - 1 && tid == 0) row_start[N] = base + T_b;
}

// Scatter via LDS cursors + fused prescale / weight-convert tail.
__global__ __launch_bounds__(256)
void scat_kernel(const int* __restrict__ src, const int* __restrict__ dst,
                 const u16* __restrict__ bh,
                 const int* __restrict__ row_start,
                 int* __restrict__ csr_src,
                 const float* __restrict__ x, const float* __restrict__ dinv,
                 unsigned* __restrict__ xs_b,
                 const float* __restrict__ W1, const float* __restrict__ W2,
                 u16* __restrict__ W1t, u16* __restrict__ W2t,
                 int E, int N, int chunk) {
    __shared__ int cur[MAXN];
    const u16* basep = bh + (size_t)blockIdx.x * N;
    for (int i = threadIdx.x; i < N; i += 256)
        cur[i] = row_start[i] + (int)basep[i];
    __syncthreads();
    int base = blockIdx.x * chunk;
    int lim = min(chunk, E - base);
    for (int i = threadIdx.x; i < lim; i += 256) {
        int e = base + i;
        int d = dst[e];
        if (d < 0 || d >= N) continue;
        int pos = atomicAdd(&cur[d], 1);
        if ((unsigned)pos < (unsigned)E) csr_src[pos] = src[e];
    }
    // ---- fused tail: prescale + W1/W2 -> f16 transposed (independent) ----
    const int total4 = N * N_FEAT / 4;
    const int stride = NB * 256;
    int g0 = blockIdx.x * 256 + threadIdx.x;
    for (int i = g0; i < total4; i += stride) {
        int row = i >> 5;                // 32 float4 per 128-f row
        float d = dinv[row];
        float4 v = ((const float4*)x)[i];
        uint2 p;
        p.x = pack_f16x2(v.x * d, v.y * d);
        p.y = pack_f16x2(v.z * d, v.w * d);
        ((uint2*)xs_b)[i] = p;
    }
    const int TOTW = N_FEAT * HID + HID * OUT_CH;
    for (int t = g0; t < TOTW; t += stride) {
        if (t < N_FEAT * HID) {          // W1t[n][k] = W1[k][n], f16 [256][128]
            int n = t >> 7, k = t & 127;
            W1t[t] = f16u(W1[(size_t)k * HID + n]);
        } else {                         // W2t[n][k] = W2[k][n], f16 [128][256]
            int j2 = t - N_FEAT * HID;
            int n = j2 >> 8, k = j2 & 255;
            W2t[j2] = f16u(W2[(size_t)k * OUT_CH + n]);
        }
    }
}

// ---------------- Aggregation: 2 nodes per wave, dual batch-8 pipelines ----
// agg is per-CU L1-miss line-throughput bound (~26us floor each at f16 width);
// all MLP-increasing variants measured neutral. Structure frozen.
__device__ __forceinline__ void agg_tail(const unsigned* __restrict__ featb,
                                         const int* __restrict__ csr_src,
                                         int e, int e1, int f,
                                         float& accx, float& accy) {
    for (; e + 4 <= e1; e += 4) {
        int s0 = csr_src[e], s1 = csr_src[e + 1];
        int s2 = csr_src[e + 2], s3 = csr_src[e + 3];
        unsigned w0 = featb[(size_t)s0 * 64 + f];
        unsigned w1 = featb[(size_t)s1 * 64 + f];
        unsigned w2 = featb[(size_t)s2 * 64 + f];
        unsigned w3 = featb[(size_t)s3 * 64 + f];
        float2 u0 = unpack_f16x2(w0), u1 = unpack_f16x2(w1);
        float2 u2 = unpack_f16x2(w2), u3 = unpack_f16x2(w3);
        accx += u0.x + u1.x + u2.x + u3.x;
        accy += u0.y + u1.y + u2.y + u3.y;
    }
    for (; e < e1; ++e) {
        float2 u = unpack_f16x2(featb[(size_t)csr_src[e] * 64 + f]);
        accx += u.x;
        accy += u.y;
    }
}

__device__ __forceinline__ void agg_full(const unsigned* __restrict__ featb,
                                         const int* __restrict__ csr_src,
                                         int e, int e1, int f,
                                         float& accx, float& accy) {
    if (e + 8 <= e1) {
        int s_cur[8];
        #pragma unroll
        for (int j = 0; j < 8; j++) s_cur[j] = csr_src[e + j];
        e += 8;
        for (; e + 8 <= e1; e += 8) {
            unsigned w[8];
            #pragma unroll
            for (int j = 0; j < 8; j++) w[j] = featb[(size_t)s_cur[j] * 64 + f];
            int s_nxt[8];
            #pragma unroll
            for (int j = 0; j < 8; j++) s_nxt[j] = csr_src[e + j];
            #pragma unroll
            for (int j = 0; j < 8; j++) {
                float2 u = unpack_f16x2(w[j]);
                accx += u.x;
                accy += u.y;
            }
            #pragma unroll
            for (int j = 0; j < 8; j++) s_cur[j] = s_nxt[j];
        }
        unsigned w[8];
        #pragma unroll
        for (int j = 0; j < 8; j++) w[j] = featb[(size_t)s_cur[j] * 64 + f];
        #pragma unroll
        for (int j = 0; j < 8; j++) {
            float2 u = unpack_f16x2(w[j]);
            accx += u.x;
            accy += u.y;
        }
    }
    agg_tail(featb, csr_src, e, e1, f, accx, accy);
}

template <bool EPILOGUE, bool F16OUT>
__global__ __launch_bounds__(256)
void agg_kernel(const unsigned* __restrict__ featb,
                const float* __restrict__ dinv,
                const int* __restrict__ row_start,
                const int* __restrict__ csr_src,
                const float* __restrict__ bias,
                void* __restrict__ out, int N) {
    int wave = threadIdx.x >> 6;
    int f = threadIdx.x & 63;
    int na = blockIdx.x * 8 + wave * 2;
    if (na >= N) return;
    int nb = na + 1;
    bool hasB = (nb < N);

    float2 va = unpack_f16x2(featb[(size_t)na * 64 + f]);
    float ax = va.x, ay = va.y;
    float bx = 0.f, by = 0.f;
    if (hasB) {
        float2 vb = unpack_f16x2(featb[(size_t)nb * 64 + f]);
        bx = vb.x;
        by = vb.y;
    }
    int ea = row_start[na], ea1 = row_start[na + 1];
    int eb = 0, eb1 = 0;
    if (hasB) { eb = ea1; eb1 = row_start[nb + 1]; }

    if (hasB && ea + 8 <= ea1 && eb + 8 <= eb1) {
        int sa[8], sb[8];
        #pragma unroll
        for (int j = 0; j < 8; j++) sa[j] = csr_src[ea + j];
        #pragma unroll
        for (int j = 0; j < 8; j++) sb[j] = csr_src[eb + j];
        ea += 8;
        eb += 8;
        while (ea + 8 <= ea1 && eb + 8 <= eb1) {
            unsigned wa[8], wb[8];
            #pragma unroll
            for (int j = 0; j < 8; j++) wa[j] = featb[(size_t)sa[j] * 64 + f];
            #pragma unroll
            for (int j = 0; j < 8; j++) wb[j] = featb[(size_t)sb[j] * 64 + f];
            int sna[8], snb[8];
            #pragma unroll
            for (int j = 0; j < 8; j++) sna[j] = csr_src[ea + j];
            #pragma unroll
            for (int j = 0; j < 8; j++) snb[j] = csr_src[eb + j];
            #pragma unroll
            for (int j = 0; j < 8; j++) {
                float2 u = unpack_f16x2(wa[j]);
                ax += u.x;
                ay += u.y;
            }
            #pragma unroll
            for (int j = 0; j < 8; j++) {
                float2 u = unpack_f16x2(wb[j]);
                bx += u.x;
                by += u.y;
            }
            #pragma unroll
            for (int j = 0; j < 8; j++) {
                sa[j] = sna[j];
                sb[j] = snb[j];
            }
            ea += 8;
            eb += 8;
        }
        unsigned wa[8], wb[8];
        #pragma unroll
        for (int j = 0; j < 8; j++) wa[j] = featb[(size_t)sa[j] * 64 + f];
        #pragma unroll
        for (int j = 0; j < 8; j++) wb[j] = featb[(size_t)sb[j] * 64 + f];
        #pragma unroll
        for (int j = 0; j < 8; j++) {
            float2 u = unpack_f16x2(wa[j]);
            ax += u.x;
            ay += u.y;
        }
        #pragma unroll
        for (int j = 0; j < 8; j++) {
            float2 u = unpack_f16x2(wb[j]);
            bx += u.x;
            by += u.y;
        }
        agg_full(featb, csr_src, ea, ea1, f, ax, ay);
        agg_full(featb, csr_src, eb, eb1, f, bx, by);
    } else {
        agg_full(featb, csr_src, ea, ea1, f, ax, ay);
        if (hasB) agg_full(featb, csr_src, eb, eb1, f, bx, by);
    }

    float dna = dinv[na];
    ax *= dna;
    ay *= dna;
    float2 bias2 = make_float2(0.f, 0.f);
    if (EPILOGUE) {
        bias2 = ((const float2*)bias)[f];
        ax = fmaxf(ax + bias2.x, 0.0f);
        ay = fmaxf(ay + bias2.y, 0.0f);
    }
    if (F16OUT) {
        ((unsigned*)out)[(size_t)na * 64 + f] = pack_f16x2(ax, ay);
    } else {
        float2 r;
        r.x = ax;
        r.y = ay;
        ((float2*)out)[(size_t)na * 64 + f] = r;
    }
    if (hasB) {
        float dnb = dinv[nb];
        bx *= dnb;
        by *= dnb;
        if (EPILOGUE) {
            bx = fmaxf(bx + bias2.x, 0.0f);
            by = fmaxf(by + bias2.y, 0.0f);
        }
        if (F16OUT) {
            ((unsigned*)out)[(size_t)nb * 64 + f] = pack_f16x2(bx, by);
        } else {
            float2 r;
            r.x = bx;
            r.y = by;
            ((float2*)out)[(size_t)nb * 64 + f] = r;
        }
    }
}

// ---------------- Fused MLP: t16 = dinv ⊙ (relu(A@W1+b1) @ W2) -------------
// Row-wise dependency only -> fuse both GEMMs per 64-row tile; H stays in LDS
// (no h16 global round-trip). MFMA f16 16x16x32, fp32 accum.
// LDS: As 16KB + W 64KB (union W1t/W2t) + H 32KB = 112KB -> 1 block/CU.
__global__ __launch_bounds__(256)
void mlp_kernel(const u16* __restrict__ A,     // [Mpad][128] f16
                const u16* __restrict__ W1t,   // [256][128] f16
                const u16* __restrict__ W2t,   // [128][256] f16
                const float* __restrict__ b1,
                const float* __restrict__ rscale,
                u16* __restrict__ C,           // [M][128] f16
                int M) {
    __shared__ __align__(16) u16 As[64 * 128];
    __shared__ __align__(16) u16 Wl[256 * 128];
    __shared__ __align__(16) u16 Hl[64 * 256];
    int tid = threadIdx.x;
    int w = tid >> 6;
    int l = tid & 63;
    int m0 = blockIdx.x * 64;
    int g = l >> 4;            // k-group 0..3
    int cl = l & 15;           // frag col/row lane index

    // stage A [64 rows x 16 chunks] and W1t [256 rows x 16 chunks], swizzled
    for (int q = tid; q < 1024; q += 256) {
        int r = q >> 4, c = q & 15;
        *(f16x8*)&As[r * 128 + ((c ^ (r & 15)) * 8)] =
            *(const f16x8*)(A + (size_t)(m0 + r) * 128 + c * 8);
    }
    for (int q = tid; q < 4096; q += 256) {
        int r = q >> 4, c = q & 15;
        *(f16x8*)&Wl[r * 128 + ((c ^ (r & 15)) * 8)] =
            *(const f16x8*)(W1t + (size_t)r * 128 + c * 8);
    }
    __syncthreads();

    // phase 1: H[64][256] = relu(A @ W1 + b1)
    {
        f32x4 acc[16];
        const f32x4 zero = {0.f, 0.f, 0.f, 0.f};
        #pragma unroll
        for (int nf = 0; nf < 16; nf++) acc[nf] = zero;
        int rowA = w * 16 + cl;
        #pragma unroll
        for (int kc = 0; kc < 4; kc++) {
            int ch = kc * 4 + g;
            f16x8 af = *(const f16x8*)&As[rowA * 128 + ((ch ^ (rowA & 15)) * 8)];
            #pragma unroll
            for (int nf = 0; nf < 16; nf++) {
                int rb = nf * 16 + cl;
                f16x8 bf = *(const f16x8*)&Wl[rb * 128 + ((ch ^ (rb & 15)) * 8)];
                acc[nf] = __builtin_amdgcn_mfma_f32_16x16x32_f16(af, bf, acc[nf], 0, 0, 0);
            }
        }
        // write H to LDS (f16, swizzled for 32-chunk rows)
        int r0 = g * 4;
        #pragma unroll
        for (int nf = 0; nf < 16; nf++) {
            int col = nf * 16 + cl;
            float bb = b1[col];
            #pragma unroll
            for (int r = 0; r < 4; r++) {
                int lr = w * 16 + r0 + r;
                float v = fmaxf(acc[nf][r] + bb, 0.0f);
                int cc = col >> 3;
                Hl[lr * 256 + ((cc ^ (lr & 31)) * 8) + (col & 7)] = f16u(v);
            }
        }
    }
    __syncthreads();

    // stage W2t [128 rows x 32 chunks] into Wl (reuse), swizzled
    for (int q = tid; q < 4096; q += 256) {
        int r = q >> 5, c = q & 31;
        *(f16x8*)&Wl[r * 256 + ((c ^ (r & 31)) * 8)] =
            *(const f16x8*)(W2t + (size_t)r * 256 + c * 8);
    }
    __syncthreads();

    // phase 2: t = dinv ⊙ (H @ W2)
    {
        f32x4 acc[8];
        const f32x4 zero = {0.f, 0.f, 0.f, 0.f};
        #pragma unroll
        for (int nf = 0; nf < 8; nf++) acc[nf] = zero;
        int rowA = w * 16 + cl;
        #pragma unroll
        for (int kc = 0; kc < 8; kc++) {
            int ch = kc * 4 + g;
            f16x8 af = *(const f16x8*)&Hl[rowA * 256 + ((ch ^ (rowA & 31)) * 8)];
            #pragma unroll
            for (int nf = 0; nf < 8; nf++) {
                int rb = nf * 16 + cl;
                f16x8 bf = *(const f16x8*)&Wl[rb * 256 + ((ch ^ (rb & 31)) * 8)];
                acc[nf] = __builtin_amdgcn_mfma_f32_16x16x32_f16(af, bf, acc[nf], 0, 0, 0);
            }
        }
        int r0 = g * 4;
        #pragma unroll
        for (int r = 0; r < 4; r++) {
            int m = m0 + w * 16 + r0 + r;
            if (m >= M) continue;
            float rs = rscale[m];
            #pragma unroll
            for (int nf = 0; nf < 8; nf++) {
                int col = nf * 16 + cl;
                C[(size_t)m * 128 + col] = f16u(acc[nf][r] * rs);
            }
        }
    }
}

// ---------------- launch ----------------

static inline size_t align512(size_t x) { return (x + 511) & ~(size_t)511; }

extern "C" void kernel_launch(void* const* d_in, const int* in_sizes, int n_in,
                              void* d_out, int out_size, void* d_ws, size_t ws_size,
                              hipStream_t stream) {
    const float* x = (const float*)d_in[0];
    const int* ei = (const int*)d_in[1];
    const float* W1 = (const float*)d_in[2];
    const float* b1 = (const float*)d_in[3];
    const float* W2 = (const float*)d_in[4];
    const float* b2 = (const float*)d_in[5];
    float* out = (float*)d_out;

    const int N = in_sizes[0] / N_FEAT;      // 10000
    const int E = in_sizes[1] / 2;           // 640000
    const int* src = ei;
    const int* dst = ei + E;

    const int Mpad = ((N + 63) / 64) * 64;   // 10048 (MFMA staging pad)

    // workspace carve-up (~19 MB)
    char* ws = (char*)d_ws;
    size_t off = 0;
    float* dinv = (float*)(ws + off);    off += align512((size_t)N * 4);
    int* flag = (int*)(ws + off);        off += align512((size_t)64 * 4);
    int* row_start = (int*)(ws + off);   off += align512((size_t)(N + 1) * 4);
    int* csr_src = (int*)(ws + off);     off += align512((size_t)E * 4);
    unsigned* xs_b = (unsigned*)(ws + off);  off += align512((size_t)N * 64 * 4);
    u16* agg1h = (u16*)(ws + off);       off += align512((size_t)Mpad * N_FEAT * 2);
    u16* t16 = (u16*)(ws + off);         off += align512((size_t)N * OUT_CH * 2);
    u16* W1t = (u16*)(ws + off);         off += align512((size_t)HID * N_FEAT * 2);
    u16* W2t = (u16*)(ws + off);         off += align512((size_t)OUT_CH * HID * 2);
    u16* bh = (u16*)(ws + off);          off += align512((size_t)NB * N * 2);
    (void)ws_size;
    const int chunk = (E + NB - 1) / NB;

    // 1. CSR build: hist -> fused colscan+scan -> scat(+prescale+Wconv)
    hist_kernel<<<NB, 256, 0, stream>>>(dst, bh, flag, E, N, chunk);
    colscan_scan_kernel<<<NJ, 256, 0, stream>>>(bh, row_start, dinv, flag, N);
    scat_kernel<<<NB, 256, 0, stream>>>(src, dst, bh, row_start, csr_src,
                                        x, dinv, xs_b, W1, W2, W1t, W2t,
                                        E, N, chunk);

    // 2. agg1h = f16(A_norm @ x)
    agg_kernel<false, true><<<(N + 7) / 8, 256, 0, stream>>>(
        xs_b, dinv, row_start, csr_src, nullptr, agg1h, N);

    // 3. t16 = dinv ⊙ (relu(agg1h @ W1 + b1) @ W2)   [fused MFMA MLP]
    mlp_kernel<<<Mpad / 64, 256, 0, stream>>>(agg1h, W1t, W2t, b1, dinv, t16, N);

    // 4. out = relu(A_norm-aggregate of t16 + b2)
    agg_kernel<true, false><<<(N + 7) / 8, 256, 0, stream>>>(
        (const unsigned*)t16, dinv, row_start, csr_src, b2, out, N);
}